// Round 4
// baseline (364.119 us; speedup 1.0000x reference)
//
#include <hip/hip_runtime.h>

// OHEM BCE loss, shape (32,1,1024,1024) fp32.
//
// Reference: k = min(100000, n_valid-1); threshold = max(kth-smallest valid
// p, 0.7); out = mean(loss over valid & p < threshold). threshold == 0.7
// whenever #{valid & p < 0.7} > k (kth order stat <= 0.7 iff >= k+1 elements
// below it), which the finalize kernel verifies. Single O(N) stream, no sort.
//
// R4: register-level MLP was defeated twice (VGPR pinned at 28-32; loads
// sunk to uses). Switch to the LDS-DMA path: global_load_lds width=16 is
// fire-and-forget (no dest VGPR, cannot be sunk), per-wave private
// double-buffered pipeline with manual s_waitcnt vmcnt(3) — no
// __syncthreads in the streaming loop, so no barrier drain.

#define OHEM_THRESH 0.7f
#define OHEM_MIN_KEPT 100000ULL
#define OHEM_IGNORE -100.0f
#define OHEM_LOG_CLAMP -100.0f

#define TPB 256
#define F4S 64    // float4 per wave per array per stage (64 lanes x 16 B = 1 KB)
#define STAGES 4  // stages per block tile; tile = 4 waves * 256 float4 = 4096 floats
#define DEPTH 2   // LDS stage buffers per wave

typedef const __attribute__((address_space(1))) void g_void;
typedef __attribute__((address_space(3))) void l_void;

__device__ __forceinline__ void ohem_elem(float pp, float tt, float ww,
                                          float& lsum, unsigned int& lcnt,
                                          unsigned int& lval) {
    bool valid = (tt != OHEM_IGNORE);
    bool sel = valid && (pp < OHEM_THRESH);
    float logp = fmaxf(__logf(pp), OHEM_LOG_CLAMP);
    float log1mp = fmaxf(__logf(1.0f - pp), OHEM_LOG_CLAMP);
    float loss = -ww * (tt * logp + (1.0f - tt) * log1mp);
    lval += valid ? 1u : 0u;
    if (sel) {
        lsum += loss;
        lcnt += 1u;
    }
}

// Issue one stage: 3 LDS-DMA loads (p,t,w), 1 KB each per wave.
// l must be wave-uniform; HW scatters lane i's 16 B to l + i*16.
__device__ __forceinline__ void stage_issue(const float4* gp, const float4* gt,
                                            const float4* gw, float4* l) {
    __builtin_amdgcn_global_load_lds((g_void*)gp, (l_void*)l, 16, 0, 0);
    __builtin_amdgcn_global_load_lds((g_void*)gt, (l_void*)(l + F4S), 16, 0, 0);
    __builtin_amdgcn_global_load_lds((g_void*)gw, (l_void*)(l + 2 * F4S), 16, 0,
                                     0);
}

// One block = 1024 float4 per array (4096 floats). Per wave: 256 float4,
// 4 stages of 64, depth-2 pipeline, fully wave-private (no __syncthreads
// until the final cross-wave reduction).
__global__ __launch_bounds__(TPB) void ohem_reduce(
    const float4* __restrict__ p4, const float4* __restrict__ t4,
    const float4* __restrict__ w4, float* __restrict__ psum,
    unsigned int* __restrict__ pcnt, unsigned int* __restrict__ pval) {
    __shared__ __attribute__((aligned(16))) float4 lds[4 * DEPTH * 3 * F4S];
    const int tid = threadIdx.x;
    const int wv = tid >> 6, lane = tid & 63;
    const size_t base =
        (size_t)blockIdx.x * 1024 + (size_t)wv * (STAGES * F4S) + lane;
    float4* ldsw = &lds[wv * (DEPTH * 3 * F4S)];  // wave-uniform

    float lsum = 0.0f;
    unsigned int lcnt = 0, lval = 0;

    stage_issue(p4 + base, t4 + base, w4 + base, ldsw);
#pragma unroll
    for (int s = 0; s < STAGES; ++s) {
        if (s + 1 < STAGES) {
            const size_t g = base + (size_t)(s + 1) * F4S;
            stage_issue(p4 + g, t4 + g, w4 + g,
                        ldsw + ((s + 1) & 1) * (3 * F4S));
            // outstanding = 6 DMA ops; wait until only the 3 newest remain,
            // i.e. stage s has fully landed in LDS.
            __builtin_amdgcn_s_waitcnt(0xF73);  // vmcnt(3), lgkm/exp no-wait
        } else {
            __builtin_amdgcn_s_waitcnt(0xF70);  // vmcnt(0)
        }
        const float4* lp = ldsw + (s & 1) * (3 * F4S);
        float4 pv = lp[lane];
        float4 tv = lp[F4S + lane];
        float4 wvv = lp[2 * F4S + lane];
        ohem_elem(pv.x, tv.x, wvv.x, lsum, lcnt, lval);
        ohem_elem(pv.y, tv.y, wvv.y, lsum, lcnt, lval);
        ohem_elem(pv.z, tv.z, wvv.z, lsum, lcnt, lval);
        ohem_elem(pv.w, tv.w, wvv.w, lsum, lcnt, lval);
    }

    // wave(64) shuffle reduction
#pragma unroll
    for (int off = 32; off > 0; off >>= 1) {
        lsum += __shfl_down(lsum, off, 64);
        lcnt += __shfl_down(lcnt, off, 64);
        lval += __shfl_down(lval, off, 64);
    }
    __shared__ float s_sum[4];
    __shared__ unsigned int s_cnt[4], s_val[4];
    if (lane == 0) {
        s_sum[wv] = lsum;
        s_cnt[wv] = lcnt;
        s_val[wv] = lval;
    }
    __syncthreads();
    if (tid == 0) {
        psum[blockIdx.x] = s_sum[0] + s_sum[1] + s_sum[2] + s_sum[3];
        pcnt[blockIdx.x] = s_cnt[0] + s_cnt[1] + s_cnt[2] + s_cnt[3];
        pval[blockIdx.x] = s_val[0] + s_val[1] + s_val[2] + s_val[3];
    }
}

// Reduces per-block partials (double accumulation), handles any leftover
// elements [tail_start, n) with scalar loads (empty for the bench shape),
// and writes the final mean.
__global__ __launch_bounds__(256) void ohem_finalize(
    const float* __restrict__ p, const float* __restrict__ t,
    const float* __restrict__ w, const float* __restrict__ psum,
    const unsigned int* __restrict__ pcnt,
    const unsigned int* __restrict__ pval, int nblocks, int tail_start, int n,
    float* __restrict__ out) {
    const int tid = threadIdx.x;
    double dsum = 0.0;
    unsigned long long cnt = 0, val = 0;
    for (int i = tid; i < nblocks; i += 256) {
        dsum += (double)psum[i];
        cnt += pcnt[i];
        val += pval[i];
    }
    for (int i = tail_start + tid; i < n; i += 256) {
        float lsum = 0.0f;
        unsigned int lcnt = 0, lval = 0;
        ohem_elem(p[i], t[i], w[i], lsum, lcnt, lval);
        dsum += (double)lsum;
        cnt += lcnt;
        val += lval;
    }
#pragma unroll
    for (int off = 32; off > 0; off >>= 1) {
        dsum += __shfl_down(dsum, off, 64);
        cnt += __shfl_down(cnt, off, 64);
        val += __shfl_down(val, off, 64);
    }
    __shared__ double s_sum[4];
    __shared__ unsigned long long s_cnt[4], s_val[4];
    const int wave = tid >> 6, lane = tid & 63;
    if (lane == 0) {
        s_sum[wave] = dsum;
        s_cnt[wave] = cnt;
        s_val[wave] = val;
    }
    __syncthreads();
    if (tid == 0) {
        double fsum = s_sum[0] + s_sum[1] + s_sum[2] + s_sum[3];
        unsigned long long fcnt = s_cnt[0] + s_cnt[1] + s_cnt[2] + s_cnt[3];
        unsigned long long fval = s_val[0] + s_val[1] + s_val[2] + s_val[3];
        if (fval == 0) {
            out[0] = __builtin_nanf("");
            return;
        }
        unsigned long long k =
            (OHEM_MIN_KEPT < fval - 1) ? OHEM_MIN_KEPT : fval - 1;
        // Guard: threshold==0.7 requires kth order stat <= 0.7, i.e. cnt > k.
        out[0] = (fcnt > k) ? (float)(fsum / (double)fcnt) : __builtin_nanf("");
    }
}

extern "C" void kernel_launch(void* const* d_in, const int* in_sizes, int n_in,
                              void* d_out, int out_size, void* d_ws,
                              size_t ws_size, hipStream_t stream) {
    const float* predict = (const float*)d_in[0];
    const float* target = (const float*)d_in[1];
    const float* weight = (const float*)d_in[2];
    float* out = (float*)d_out;
    const int n = in_sizes[0];
    const int n4 = n >> 2;
    const int full_blocks = n4 / 1024;  // blocks fully covered by DMA tiles

    float* psum = (float*)d_ws;
    unsigned int* pcnt = (unsigned int*)(psum + (full_blocks > 0 ? full_blocks : 1));
    unsigned int* pval = pcnt + (full_blocks > 0 ? full_blocks : 1);

    if (full_blocks > 0) {
        hipLaunchKernelGGL(ohem_reduce, dim3(full_blocks), dim3(TPB), 0,
                           stream, (const float4*)predict,
                           (const float4*)target, (const float4*)weight, psum,
                           pcnt, pval);
    }
    hipLaunchKernelGGL(ohem_finalize, dim3(1), dim3(256), 0, stream, predict,
                       target, weight, psum, pcnt, pval, full_blocks,
                       full_blocks * 4096, n, out);
}